// Round 3
// baseline (199.452 us; speedup 1.0000x reference)
//
#include <hip/hip_runtime.h>

typedef unsigned int uint;

#define B_ 64
#define T_ 512
#define K_ 10
constexpr float TEMP_ = 0.07f;
constexpr float EPS_ = 1e-8f;
constexpr int F4ROW = 256;          // float4 per 1024-f32 row
constexpr int APW = 8;              // anchors per wave
constexpr int NBLK = 16;            // blocks per b (4 waves * 8 anchors = 32/block)

__device__ __forceinline__ float plo_(uint u){ return __uint_as_float(u << 16); }
__device__ __forceinline__ float phi_(uint u){ return __uint_as_float(u & 0xffff0000u); }
__device__ __forceinline__ uint bfr_(float f){
    uint u = __float_as_uint(f);
    return (u + 0x7fffu + ((u >> 16) & 1u)) >> 16;
}
__device__ __forceinline__ uint pack2_(float lo, float hi){ return bfr_(lo) | (bfr_(hi) << 16); }

// 64-lane all-reduce: 4x DPP row_ror (16-lane) + ds_swizzle xor16 + shfl_xor 32
template <int CTRL>
__device__ __forceinline__ float dpp_add(float x){
    int y = __builtin_amdgcn_update_dpp(0, __float_as_int(x), CTRL, 0xf, 0xf, false);
    return x + __int_as_float(y);
}
__device__ __forceinline__ float red64(float x){
    x = dpp_add<0x128>(x);
    x = dpp_add<0x124>(x);
    x = dpp_add<0x122>(x);
    x = dpp_add<0x121>(x);
    int y = __builtin_amdgcn_ds_swizzle(__float_as_int(x), 0x401F);
    x += __int_as_float(y);
    x += __shfl_xor(x, 32, 64);
    return x;
}

// lane's 16-col slice of a row: cols [8l, 8l+8) and [512+8l, 512+8l+8)
struct R16 { float f[16]; };

__device__ __forceinline__ void load_row(const float4* __restrict__ p, int l2, R16& r){
    *reinterpret_cast<float4*>(&r.f[0])  = p[l2];
    *reinterpret_cast<float4*>(&r.f[4])  = p[l2 + 1];
    *reinterpret_cast<float4*>(&r.f[8])  = p[l2 + 128];
    *reinterpret_cast<float4*>(&r.f[12]) = p[l2 + 129];
}

__global__ __launch_bounds__(256, 3) void signcl_main(
    const float* __restrict__ features,
    const int* __restrict__ neg_b,
    const int* __restrict__ neg_t,
    float* __restrict__ partials)
{
    __shared__ float s_part[4];
    const int tid = threadIdx.x;
    const int l = tid & 63, w = tid >> 6;
    const int l2 = l * 2;
    const int bid = blockIdx.x;
    const int b = bid >> 4;                 // / NBLK
    const int c = bid & (NBLK - 1);

    const float4* f4 = reinterpret_cast<const float4*>(features);
    const float4* fb = f4 + (size_t)b * T_ * F4ROW;

    // ---- prologue: 10 normalized negatives, bf16-packed, register-resident ----
    uint npk[K_ * 8];
#pragma unroll
    for (int k = 0; k < K_; ++k){
        int nb = neg_b[b * K_ + k];
        int nt = neg_t[b * K_ + k];
        R16 n; load_row(f4 + ((size_t)nb * T_ + nt) * F4ROW, l2, n);
        float ss = 0.f;
#pragma unroll
        for (int i = 0; i < 16; ++i) ss = fmaf(n.f[i], n.f[i], ss);
        ss = red64(ss);
        float inv = 1.f / fmaxf(sqrtf(ss), EPS_);
#pragma unroll
        for (int j = 0; j < 8; ++j)
            npk[k*8+j] = pack2_(n.f[2*j] * inv, n.f[2*j+1] * inv);
    }

    // ---- register row-walk over anchors [ta, ta+APW) ----
    const int ta = 1 + c * 32 + w * APW;    // 1..505
    R16 cur; load_row(fb + (size_t)ta * F4ROW, l2, cur);
    float ssc = 0.f;
#pragma unroll
    for (int i = 0; i < 16; ++i) ssc = fmaf(cur.f[i], cur.f[i], ssc);
    float inv_c = 1.f / fmaxf(sqrtf(red64(ssc)), EPS_);

    const float invT = 1.f / TEMP_;
    float lsum = 0.f;

#pragma unroll 2
    for (int i = 0; i < APW; ++i){
        int t = ta + i;
        int tn = (t + 1 <= T_ - 1) ? t + 1 : T_ - 1;
        R16 nxt; load_row(fb + (size_t)tn * F4ROW, l2, nxt);  // issued early

        // neg dots on cur only — hides the nxt load latency
        float nd[K_];
#pragma unroll
        for (int k = 0; k < K_; ++k){
            float a = 0.f;
#pragma unroll
            for (int j = 0; j < 8; ++j){
                uint u = npk[k*8+j];
                a = fmaf(cur.f[2*j],   plo_(u), a);
                a = fmaf(cur.f[2*j+1], phi_(u), a);
            }
            nd[k] = a;
        }
#pragma unroll
        for (int k = 0; k < K_; ++k) nd[k] = red64(nd[k]);

        float ssn = 0.f, dp = 0.f;
#pragma unroll
        for (int q = 0; q < 16; ++q){
            ssn = fmaf(nxt.f[q], nxt.f[q], ssn);
            dp  = fmaf(cur.f[q], nxt.f[q], dp);
        }
        ssn = red64(ssn);
        dp  = red64(dp);
        float inv_n = 1.f / fmaxf(sqrtf(ssn), EPS_);

        if (t <= T_ - 2){                   // anchors t = 1..510
            float pos = dp * inv_c * inv_n * invT;
            float sc = inv_c * invT;
            float se = 0.f;
#pragma unroll
            for (int k = 0; k < K_; ++k) se += __expf(nd[k] * sc);
            lsum += __logf(__expf(pos) + se) - pos;
        }
        cur = nxt; inv_c = inv_n;
    }

    if (l == 0) s_part[w] = lsum;           // all lanes hold identical lsum post-red64
    __syncthreads();
    if (tid == 0) partials[bid] = s_part[0] + s_part[1] + s_part[2] + s_part[3];
}

__global__ __launch_bounds__(256) void signcl_reduce(
    const float* __restrict__ partials, float* __restrict__ out)
{
    __shared__ float s_w[4];
    const int tid = threadIdx.x;
    float s = 0.f;
    for (int idx = tid; idx < B_ * NBLK; idx += 256) s += partials[idx];
#pragma unroll
    for (int m = 32; m >= 1; m >>= 1) s += __shfl_xor(s, m, 64);
    const int w = tid >> 6, lane = tid & 63;
    if (lane == 0) s_w[w] = s;
    __syncthreads();
    if (tid == 0) {
        float t = s_w[0] + s_w[1] + s_w[2] + s_w[3];
        out[0] = t / (float)(B_ * (T_ - 2));
    }
}

extern "C" void kernel_launch(void* const* d_in, const int* in_sizes, int n_in,
                              void* d_out, int out_size, void* d_ws, size_t ws_size,
                              hipStream_t stream) {
    const float* features = (const float*)d_in[0];
    const int* neg_b = (const int*)d_in[1];
    const int* neg_t = (const int*)d_in[2];
    float* partials = (float*)d_ws;          // 1024 floats, fully overwritten each call

    signcl_main<<<B_ * NBLK, 256, 0, stream>>>(features, neg_b, neg_t, partials);
    signcl_reduce<<<1, 256, 0, stream>>>(partials, (float*)d_out);
}

// Round 4
// 43.549 us; speedup vs baseline: 4.5800x; 4.5800x over previous
//
#include <hip/hip_runtime.h>

typedef unsigned int uint;

#define B_ 64
#define T_ 512
#define K_ 10
constexpr float TEMP_ = 0.07f;
constexpr float EPS_ = 1e-8f;
constexpr int F4ROW = 256;          // float4 per 1024-f32 row
constexpr int APW = 4;              // anchors per wave
constexpr int NBLK = 32;            // blocks per b (4 waves * 4 anchors = 16 anchors/block)
constexpr int ROWU = 512;           // packed uints per neg row (2 bf16 each)

__device__ __forceinline__ float dot4(float4 a, float4 b) {
    return a.x * b.x + a.y * b.y + a.z * b.z + a.w * b.w;
}
__device__ __forceinline__ float plo_(uint u){ return __uint_as_float(u << 16); }
__device__ __forceinline__ float phi_(uint u){ return __uint_as_float(u & 0xffff0000u); }
__device__ __forceinline__ uint bfr_(float f){
    uint u = __float_as_uint(f);
    return (u + 0x7fffu + ((u >> 16) & 1u)) >> 16;
}
__device__ __forceinline__ uint pack2_(float lo, float hi){ return bfr_(lo) | (bfr_(hi) << 16); }

// 64-lane all-reduce: 4x DPP row_ror (16-lane) + ds_swizzle xor16 + shfl_xor 32
template <int CTRL>
__device__ __forceinline__ float dpp_add(float x){
    int y = __builtin_amdgcn_update_dpp(0, __float_as_int(x), CTRL, 0xf, 0xf, false);
    return x + __int_as_float(y);
}
__device__ __forceinline__ float red64(float x){
    x = dpp_add<0x128>(x);
    x = dpp_add<0x124>(x);
    x = dpp_add<0x122>(x);
    x = dpp_add<0x121>(x);
    int y = __builtin_amdgcn_ds_swizzle(__float_as_int(x), 0x401F); // xor lane^16
    x += __int_as_float(y);
    x += __shfl_xor(x, 32, 64);
    return x;
}

// ---- prep: one wave per (b,k); normalized bf16-packed neg rows in lane-permuted order ----
// layout per row: uint4 index (h*64 + l) holds cols [16l+8h, 16l+8h+8) as 4 bf16-pairs
__global__ __launch_bounds__(64) void signcl_prep(
    const float* __restrict__ features,
    const int* __restrict__ neg_b,
    const int* __restrict__ neg_t,
    uint* __restrict__ negs_pk)
{
    const int blk = blockIdx.x;
    const int b = blk / K_, k = blk % K_;
    const int l = threadIdx.x;              // 0..63

    const int nb = neg_b[b * K_ + k];
    const int nt = neg_t[b * K_ + k];
    const float4* rp = reinterpret_cast<const float4*>(features)
                       + ((size_t)nb * T_ + nt) * F4ROW + l * 4;
    float4 v0 = rp[0], v1 = rp[1], v2 = rp[2], v3 = rp[3];
    float ss = dot4(v0, v0) + dot4(v1, v1) + dot4(v2, v2) + dot4(v3, v3);
    ss = red64(ss);
    const float inv = 1.f / fmaxf(sqrtf(ss), EPS_);

    uint4* out = reinterpret_cast<uint4*>(negs_pk + ((size_t)b * K_ + k) * ROWU);
    uint4 o;
    o.x = pack2_(v0.x * inv, v0.y * inv);
    o.y = pack2_(v0.z * inv, v0.w * inv);
    o.z = pack2_(v1.x * inv, v1.y * inv);
    o.w = pack2_(v1.z * inv, v1.w * inv);
    out[l] = o;
    o.x = pack2_(v2.x * inv, v2.y * inv);
    o.y = pack2_(v2.z * inv, v2.w * inv);
    o.z = pack2_(v3.x * inv, v3.y * inv);
    o.w = pack2_(v3.z * inv, v3.w * inv);
    out[64 + l] = o;
}

// ---- main: LDS-resident packed negs, register double-buffered row walk ----
__global__ __launch_bounds__(256) void signcl_main(
    const float* __restrict__ features,
    const uint* __restrict__ negs_pk,
    float* __restrict__ partials)
{
    __shared__ uint s_negs[K_ * ROWU];      // 20480 B
    __shared__ float s_part[4];

    const int tid = threadIdx.x;
    const int l = tid & 63, w = tid >> 6;
    const int bid = blockIdx.x;
    const int b = bid >> 5;                 // / NBLK
    const int c = bid & (NBLK - 1);

    // stage packed negs (contiguous vector copy)
    {
        const uint4* gsrc = reinterpret_cast<const uint4*>(negs_pk + (size_t)b * K_ * ROWU);
        uint4* sdst = reinterpret_cast<uint4*>(s_negs);
#pragma unroll
        for (int j = 0; j < 5; ++j) sdst[tid + j * 256] = gsrc[tid + j * 256];
    }
    __syncthreads();

    const float4* fb = reinterpret_cast<const float4*>(features) + (size_t)b * T_ * F4ROW;
    const uint4* n4 = reinterpret_cast<const uint4*>(s_negs);
    const int ta = 1 + c * 16 + w * APW;    // 1..509; slots t=1..512, valid t<=510

    const float4* rp = fb + (size_t)ta * F4ROW + l * 4;
    float4 A0 = rp[0], A1 = rp[1], A2 = rp[2], A3 = rp[3];
    float ssc = dot4(A0, A0) + dot4(A1, A1) + dot4(A2, A2) + dot4(A3, A3);
    float inv_c = 1.f / fmaxf(sqrtf(red64(ssc)), EPS_);

    const float invT = 1.f / TEMP_;
    float lsum = 0.f;

#pragma unroll
    for (int i = 0; i < APW; ++i){
        const int t = ta + i;
        const int tn = (t + 1 < T_ - 1) ? (t + 1) : (T_ - 1);
        const float4* rn = fb + (size_t)tn * F4ROW + l * 4;
        float4 N0 = rn[0], N1 = rn[1], N2 = rn[2], N3 = rn[3];   // issued early

        // 10 neg dots on cur only (hides the N-load latency)
        float nd[K_];
#pragma unroll
        for (int k = 0; k < K_; ++k){
            uint4 u0 = n4[k * 128 + l];        // cols [16l, 16l+8)
            uint4 u1 = n4[k * 128 + 64 + l];   // cols [16l+8, 16l+16)
            float a;
            a = fmaf(A0.x, plo_(u0.x), 0.f);
            a = fmaf(A0.y, phi_(u0.x), a);
            a = fmaf(A0.z, plo_(u0.y), a);
            a = fmaf(A0.w, phi_(u0.y), a);
            a = fmaf(A1.x, plo_(u0.z), a);
            a = fmaf(A1.y, phi_(u0.z), a);
            a = fmaf(A1.z, plo_(u0.w), a);
            a = fmaf(A1.w, phi_(u0.w), a);
            a = fmaf(A2.x, plo_(u1.x), a);
            a = fmaf(A2.y, phi_(u1.x), a);
            a = fmaf(A2.z, plo_(u1.y), a);
            a = fmaf(A2.w, phi_(u1.y), a);
            a = fmaf(A3.x, plo_(u1.z), a);
            a = fmaf(A3.y, phi_(u1.z), a);
            a = fmaf(A3.z, plo_(u1.w), a);
            a = fmaf(A3.w, phi_(u1.w), a);
            nd[k] = a;
        }
#pragma unroll
        for (int k = 0; k < K_; ++k) nd[k] = red64(nd[k]);

        float ssn = dot4(N0, N0) + dot4(N1, N1) + dot4(N2, N2) + dot4(N3, N3);
        float dp  = dot4(A0, N0) + dot4(A1, N1) + dot4(A2, N2) + dot4(A3, N3);
        ssn = red64(ssn);
        dp  = red64(dp);
        const float inv_n = 1.f / fmaxf(sqrtf(ssn), EPS_);

        if (t <= T_ - 2){
            float pos = dp * inv_c * inv_n * invT;
            float sc = inv_c * invT;
            float se = 0.f;
#pragma unroll
            for (int k = 0; k < K_; ++k) se += __expf(nd[k] * sc);
            lsum += __logf(__expf(pos) + se) - pos;
        }
        A0 = N0; A1 = N1; A2 = N2; A3 = N3; inv_c = inv_n;
    }

    if (l == 0) s_part[w] = lsum;           // identical across lanes post-red64
    __syncthreads();
    if (tid == 0) partials[bid] = s_part[0] + s_part[1] + s_part[2] + s_part[3];
}

__global__ __launch_bounds__(256) void signcl_reduce(
    const float* __restrict__ partials, float* __restrict__ out)
{
    __shared__ float s_w[4];
    const int tid = threadIdx.x;
    float s = 0.f;
    for (int idx = tid; idx < B_ * NBLK; idx += 256) s += partials[idx];
#pragma unroll
    for (int m = 32; m >= 1; m >>= 1) s += __shfl_xor(s, m, 64);
    const int w = tid >> 6, lane = tid & 63;
    if (lane == 0) s_w[w] = s;
    __syncthreads();
    if (tid == 0) {
        float t = s_w[0] + s_w[1] + s_w[2] + s_w[3];
        out[0] = t / (float)(B_ * (T_ - 2));
    }
}

extern "C" void kernel_launch(void* const* d_in, const int* in_sizes, int n_in,
                              void* d_out, int out_size, void* d_ws, size_t ws_size,
                              hipStream_t stream) {
    const float* features = (const float*)d_in[0];
    const int* neg_b = (const int*)d_in[1];
    const int* neg_t = (const int*)d_in[2];
    uint* negs_pk = (uint*)d_ws;                               // 1.31 MB packed negs
    float* partials = (float*)((char*)d_ws + (2u << 20));      // 2048 floats at +2 MB

    signcl_prep<<<B_ * K_, 64, 0, stream>>>(features, neg_b, neg_t, negs_pk);
    signcl_main<<<B_ * NBLK, 256, 0, stream>>>(features, negs_pk, partials);
    signcl_reduce<<<1, 256, 0, stream>>>(partials, (float*)d_out);
}